// Round 1
// baseline (436.733 us; speedup 1.0000x reference)
//
#include <hip/hip_runtime.h>
#include <cstddef>

#define B_ 4
#define H_ 16
#define L_ 8192
#define D_ 64
#define BH_ (B_ * H_)

// 8192^(-0.25)
#define SCALE 0.1051120519067143f

__device__ __forceinline__ float elu1(float x) {
    // elu(x) + 1
    return x > 0.0f ? (x + 1.0f) : __expf(x);
}

// ---------------------------------------------------------------------------
// Zero the KV workspace: BH*64*64 floats = 262144 floats = 65536 float4
// grid 256 x 256 threads
// ---------------------------------------------------------------------------
__global__ __launch_bounds__(256) void zero_kernel(float4* __restrict__ p) {
    p[(size_t)blockIdx.x * 256 + threadIdx.x] = make_float4(0.f, 0.f, 0.f, 0.f);
}

// ---------------------------------------------------------------------------
// Phase 1: KV[bh][d][e] += sum_l Kf[l][d] * Vm[l][e]
// grid (BH=64, L/512=16), 256 threads.
// Wave w (=tid>>6) owns d in [16w, 16w+16); lane owns e = tid&63.
// ---------------------------------------------------------------------------
__global__ __launch_bounds__(256) void kv_kernel(
    const float* __restrict__ K, const float* __restrict__ V,
    const float* __restrict__ mask, const float* __restrict__ pi,
    const float* __restrict__ mu, float* __restrict__ kv)
{
    const int bh = blockIdx.x;
    const int b = bh >> 4;       // H = 16
    const int h = bh & 15;
    const int l0 = blockIdx.y * 512;
    const int t = threadIdx.x;
    const int lane_e = t & 63;
    const int dbase = (t >> 6) * 16;

    __shared__ float muc[64];
    __shared__ float sK[32][64];
    __shared__ float sV[32][64];

    float p0 = fminf(fmaxf(pi[0], 0.f), 1.f);
    float p1 = fminf(fmaxf(pi[1], 0.f), 1.f);
    const float psum = p0 + p1;
    if (t < 64) {
        muc[t] = p0 * mu[h * D_ + t] + p1 * mu[(H_ + h) * D_ + t];
    }
    __syncthreads();

    const float* Kb = K + (size_t)bh * L_ * D_;
    const float* Vb = V + (size_t)bh * L_ * D_;
    const float* mb = mask + (size_t)b * L_;

    // Two float4 load slots per thread per array (32*16 = 512 float4 / 256 thr)
    const int r0 = t >> 4;             // rows 0..15
    const int c0 = (t & 15) * 4;
    const int r1 = (t + 256) >> 4;     // rows 16..31
    const int c1 = c0;                 // same column pattern

    const float4 mu0 = *(const float4*)&muc[c0];
    const float4 mu1 = *(const float4*)&muc[c1];

    float acc[16];
#pragma unroll
    for (int i = 0; i < 16; ++i) acc[i] = 0.f;

    for (int tile = 0; tile < 512; tile += 32) {
        const int lb = l0 + tile;
        // ---- stage slot 0 ----
        {
            const int l = lb + r0;
            const float m = mb[l];
            const float sm = SCALE * m;
            float4 k = *(const float4*)(Kb + (size_t)l * D_ + c0);
            float4 o;
            o.x = elu1(k.x * psum - mu0.x) * sm;
            o.y = elu1(k.y * psum - mu0.y) * sm;
            o.z = elu1(k.z * psum - mu0.z) * sm;
            o.w = elu1(k.w * psum - mu0.w) * sm;
            *(float4*)&sK[r0][c0] = o;
            float4 v = *(const float4*)(Vb + (size_t)l * D_ + c0);
            v.x *= m; v.y *= m; v.z *= m; v.w *= m;
            *(float4*)&sV[r0][c0] = v;
        }
        // ---- stage slot 1 ----
        {
            const int l = lb + r1;
            const float m = mb[l];
            const float sm = SCALE * m;
            float4 k = *(const float4*)(Kb + (size_t)l * D_ + c1);
            float4 o;
            o.x = elu1(k.x * psum - mu1.x) * sm;
            o.y = elu1(k.y * psum - mu1.y) * sm;
            o.z = elu1(k.z * psum - mu1.z) * sm;
            o.w = elu1(k.w * psum - mu1.w) * sm;
            *(float4*)&sK[r1][c1] = o;
            float4 v = *(const float4*)(Vb + (size_t)l * D_ + c1);
            v.x *= m; v.y *= m; v.z *= m; v.w *= m;
            *(float4*)&sV[r1][c1] = v;
        }
        __syncthreads();

#pragma unroll
        for (int l = 0; l < 32; ++l) {
            const float v = sV[l][lane_e];
            const float4 ka = *(const float4*)&sK[l][dbase];
            const float4 kb = *(const float4*)&sK[l][dbase + 4];
            const float4 kc = *(const float4*)&sK[l][dbase + 8];
            const float4 kd = *(const float4*)&sK[l][dbase + 12];
            acc[0]  += ka.x * v;  acc[1]  += ka.y * v;
            acc[2]  += ka.z * v;  acc[3]  += ka.w * v;
            acc[4]  += kb.x * v;  acc[5]  += kb.y * v;
            acc[6]  += kb.z * v;  acc[7]  += kb.w * v;
            acc[8]  += kc.x * v;  acc[9]  += kc.y * v;
            acc[10] += kc.z * v;  acc[11] += kc.w * v;
            acc[12] += kd.x * v;  acc[13] += kd.y * v;
            acc[14] += kd.z * v;  acc[15] += kd.w * v;
        }
        __syncthreads();
    }

    float* kvp = kv + (size_t)bh * (D_ * D_);
#pragma unroll
    for (int j = 0; j < 16; ++j)
        atomicAdd(kvp + (dbase + j) * D_ + lane_e, acc[j]);
}

// ---------------------------------------------------------------------------
// Phase 2: out[l][e] = sum_d Qf[l][d] * KV[d][e]
// grid (BH=64, L/64=128), 256 threads. Thread owns a 4l x 4e register tile.
// ---------------------------------------------------------------------------
__global__ __launch_bounds__(256) void out_kernel(
    const float* __restrict__ Q, const float* __restrict__ kv,
    float* __restrict__ out)
{
    const int bh = blockIdx.x;
    const int l0 = blockIdx.y * 64;
    const int t = threadIdx.x;

    __shared__ float sKV[64][64];   // 16 KB
    __shared__ float sQ[64][65];    // padded, ~16.6 KB

    const float* Qb = Q + (size_t)bh * L_ * D_ + (size_t)l0 * D_;
    const float* kvp = kv + (size_t)bh * (D_ * D_);

    // load KV: 1024 float4, 4 per thread
#pragma unroll
    for (int i = 0; i < 4; ++i) {
        const int idx = t + i * 256;
        *(float4*)&sKV[idx >> 4][(idx & 15) * 4] = *(const float4*)(kvp + (size_t)idx * 4);
    }
    // load Q tile with transform (scalar LDS writes; pad-65 keeps banks clean)
#pragma unroll
    for (int i = 0; i < 4; ++i) {
        const int idx = t + i * 256;
        const int row = idx >> 4;
        const int col = (idx & 15) * 4;
        const float4 q = *(const float4*)(Qb + (size_t)idx * 4);
        sQ[row][col + 0] = elu1(q.x) * SCALE;
        sQ[row][col + 1] = elu1(q.y) * SCALE;
        sQ[row][col + 2] = elu1(q.z) * SCALE;
        sQ[row][col + 3] = elu1(q.w) * SCALE;
    }
    __syncthreads();

    const int te = t & 15;
    const int tl = t >> 4;
    const int e0 = te * 4;
    const int lb = tl * 4;

    float acc[16];
#pragma unroll
    for (int i = 0; i < 16; ++i) acc[i] = 0.f;

#pragma unroll 16
    for (int d = 0; d < 64; ++d) {
        const float4 k4 = *(const float4*)&sKV[d][e0];
        const float q0 = sQ[lb + 0][d];
        const float q1 = sQ[lb + 1][d];
        const float q2 = sQ[lb + 2][d];
        const float q3 = sQ[lb + 3][d];
        acc[0]  += q0 * k4.x;  acc[1]  += q0 * k4.y;
        acc[2]  += q0 * k4.z;  acc[3]  += q0 * k4.w;
        acc[4]  += q1 * k4.x;  acc[5]  += q1 * k4.y;
        acc[6]  += q1 * k4.z;  acc[7]  += q1 * k4.w;
        acc[8]  += q2 * k4.x;  acc[9]  += q2 * k4.y;
        acc[10] += q2 * k4.z;  acc[11] += q2 * k4.w;
        acc[12] += q3 * k4.x;  acc[13] += q3 * k4.y;
        acc[14] += q3 * k4.z;  acc[15] += q3 * k4.w;
    }

    float* ob = out + (size_t)bh * L_ * D_ + (size_t)l0 * D_;
#pragma unroll
    for (int i = 0; i < 4; ++i) {
        float4 r;
        r.x = acc[i * 4 + 0];
        r.y = acc[i * 4 + 1];
        r.z = acc[i * 4 + 2];
        r.w = acc[i * 4 + 3];
        *(float4*)(ob + (size_t)(lb + i) * D_ + e0) = r;
    }
}

extern "C" void kernel_launch(void* const* d_in, const int* in_sizes, int n_in,
                              void* d_out, int out_size, void* d_ws, size_t ws_size,
                              hipStream_t stream) {
    (void)in_sizes; (void)n_in; (void)out_size; (void)ws_size;
    const float* Q    = (const float*)d_in[0];
    const float* K    = (const float*)d_in[1];
    const float* V    = (const float*)d_in[2];
    const float* mask = (const float*)d_in[3];
    const float* pi   = (const float*)d_in[4];
    const float* mu   = (const float*)d_in[5];
    float* out = (float*)d_out;
    float* kvw = (float*)d_ws;   // BH*64*64 floats = 1 MiB

    zero_kernel<<<256, 256, 0, stream>>>((float4*)kvw);
    kv_kernel<<<dim3(BH_, 16), 256, 0, stream>>>(K, V, mask, pi, mu, kvw);
    out_kernel<<<dim3(BH_, 128), 256, 0, stream>>>(Q, kvw, out);
}